// Round 6
// baseline (346.468 us; speedup 1.0000x reference)
//
#include <hip/hip_runtime.h>

#define LTC_B 512
#define LTC_H 512
#define LTC_I 256

static constexpr float kL2E = 1.4426950408889634f;  // log2(e)

typedef _Float16 half2v __attribute__((ext_vector_type(2)));
typedef __fp16   fp16x2 __attribute__((ext_vector_type(2)));
typedef unsigned int u32;

// Per j-pair, per h: t = a*v + c (log2 domain), sig = 1/(1+2^t).
// a,c kept in f32 (no cvt tax); weights packed f16 for v_dot2_f32_f16.
struct alignas(8) WPair { half2v wz, wd; };       // (wz0,wz1),(wd0,wd1)

#define AS_G __attribute__((address_space(1)))
#define AS_L __attribute__((address_space(3)))

__device__ __forceinline__ void ldg_lds16(const void* g, void* l) {
    // async global->LDS DMA, 16B/lane; LDS dest = wave-uniform base + lane*16
    __builtin_amdgcn_global_load_lds((const AS_G u32*)g, (AS_L u32*)l, 16, 0, 0);
}

// ac slab: float4 (a0,a1,c0,c1) at unit ((ht*(K/2)+jp)*64+hh)  -> 16B
// w  slab: WPair                 at the same unit index         -> 8B
// A 16-j chunk of one h-tile = contiguous 8KB (ac) + 4KB (w).
template<int K>
__global__ void ltc_prep(const float* __restrict__ mu, const float* __restrict__ sigma,
                         const float* __restrict__ W, const float* __restrict__ erev,
                         float4* __restrict__ acs, WPair* __restrict__ wps) {
    const int t = blockIdx.x * 256 + threadIdx.x;   // one thread per unit
    if (t >= K * 256) return;
    const int hh   = t & 63;
    const int rest = t >> 6;
    const int jp   = rest & (K / 2 - 1);
    const int ht   = rest / (K / 2);
    const int h    = ht * 64 + hh;
    const int g0   = (2 * jp) * LTC_H + h;
    const int g1   = g0 + LTC_H;
    const float sg0 = sigma[g0], sg1 = sigma[g1];
    acs[t] = make_float4(-sg0 * kL2E, -sg1 * kL2E,
                         mu[g0] * sg0 * kL2E, mu[g1] * sg1 * kL2E);
    WPair o;
    o.wz[0] = (_Float16)(W[g0] * erev[g0]);
    o.wz[1] = (_Float16)(W[g1] * erev[g1]);
    o.wd[0] = (_Float16)(W[g0]);
    o.wd[1] = (_Float16)(W[g1]);
    wps[t] = o;
}

// Block = 256 thr (4 waves), wave owns 1 b-row x 64 h. Grid (8, B/4) = 1024
// blocks -> 4 blocks/CU. In-order chunks (linear id % 8 == ht -> each XCD's
// L2 only holds its own h-tile slice). Double-buffered 12KB chunks.
template<int K, bool RECUR>
__global__ __launch_bounds__(256, 4)
void ltc_pass(const float* __restrict__ vsrc,    // B x K
              const float4* __restrict__ acs,    // [8][K/2][64]
              const WPair*  __restrict__ wps,    // [8][K/2][64]
              const float* __restrict__ snum, const float* __restrict__ sden,
              const float* __restrict__ vleak, const float* __restrict__ gleak,
              const float* __restrict__ cm,
              float* __restrict__ onum, float* __restrict__ oden,
              float* __restrict__ vout)
{
    constexpr int JC = 16;                       // j per chunk
    constexpr int PC = JC / 2;                   // pairs per chunk = 8
    constexpr int NC = K / JC;
    __shared__ float4 acb[2][PC * 64];           // 2 x 8KB
    __shared__ WPair  wpb[2][PC * 64];           // 2 x 4KB
    const int tid  = threadIdx.x;
    const int lane = tid & 63;
    const int wu   = __builtin_amdgcn_readfirstlane(tid >> 6);  // 0..3
    const int ht   = blockIdx.x;                 // 0..7
    const int b    = blockIdx.y * 4 + wu;        // uniform per wave
    const float* __restrict__ vrow = vsrc + (size_t)b * K;      // -> s_load

    const char* acg = (const char*)acs + (size_t)ht * (K * 512);  // (K/2)*64*16
    const char* wpg = (const char*)wps + (size_t)ht * (K * 256);  // (K/2)*64*8

    // prefetch chunk 0: ac = 8 x 1KB rows (waves take wu, wu+4), w = 4 x 1KB
    {
        char* acd = (char*)&acb[0][0];
        char* wpd = (char*)&wpb[0][0];
        ldg_lds16(acg + wu * 1024 + lane * 16,       acd + wu * 1024);
        ldg_lds16(acg + (wu + 4) * 1024 + lane * 16, acd + (wu + 4) * 1024);
        ldg_lds16(wpg + wu * 1024 + lane * 16,       wpd + wu * 1024);
    }

    float na = 0.f, da = 0.f;

    #pragma unroll
    for (int i = 0; i < NC; ++i) {
        __syncthreads();                         // drains chunk i's DMA + joins
        if (i + 1 < NC) {                        // DMA i+1 flies during compute i
            const char* as = acg + (i + 1) * 8192;
            const char* ps = wpg + (i + 1) * 4096;
            char* acd = (char*)&acb[(i + 1) & 1][0];
            char* wpd = (char*)&wpb[(i + 1) & 1][0];
            ldg_lds16(as + wu * 1024 + lane * 16,       acd + wu * 1024);
            ldg_lds16(as + (wu + 4) * 1024 + lane * 16, acd + (wu + 4) * 1024);
            ldg_lds16(ps + wu * 1024 + lane * 16,       wpd + wu * 1024);
        }
        const float4* ab = &acb[i & 1][0];
        const WPair*  pb = &wpb[i & 1][0];
        const float* __restrict__ vch = vrow + i * JC;

        #pragma unroll
        for (int jj = 0; jj < PC; ++jj) {
            const float4 ac = ab[jj * 64 + lane];   // ds_read_b128
            const WPair  wp = pb[jj * 64 + lane];   // ds_read_b64
            const float vj0 = vch[2 * jj];          // uniform -> s_load
            const float vj1 = vch[2 * jj + 1];
            const float t0 = fmaf(ac.x, vj0, ac.z); // pure f32, no cvt
            const float t1 = fmaf(ac.y, vj1, ac.w);
            const float e0 = __builtin_amdgcn_exp2f(t0);
            const float e1 = __builtin_amdgcn_exp2f(t1);
            const float d0 = 1.0f + e0;
            const float d1 = 1.0f + e1;
            const float rr = __builtin_amdgcn_rcpf(d0 * d1);  // 1 rcp / 2 sig
            const float s0 = rr * d1;
            const float s1 = rr * d0;
            const fp16x2 spraw = __builtin_amdgcn_cvt_pkrtz(s0, s1);  // v_cvt_pkrtz
            const half2v sp = __builtin_bit_cast(half2v, spraw);
#if defined(__has_builtin) && __has_builtin(__builtin_amdgcn_fdot2)
            na = __builtin_amdgcn_fdot2(wp.wz, sp, na, false);  // v_dot2_f32_f16
            da = __builtin_amdgcn_fdot2(wp.wd, sp, da, false);
#else
            na = fmaf((float)wp.wz[0], s0, fmaf((float)wp.wz[1], s1, na));
            da = fmaf((float)wp.wd[0], s0, fmaf((float)wp.wd[1], s1, da));
#endif
        }
    }

    const int h  = ht * 64 + lane;
    const int bh = b * LTC_H + h;
    if constexpr (RECUR) {
        const float gl = gleak[h], vl = vleak[h], c0 = cm[h];
        const float vp = vrow[h];                // K==H here
        const float num = fmaf(c0, vp, gl * vl) + na + snum[bh];
        const float den = c0 + gl + da + sden[bh];
        vout[bh] = num * __builtin_amdgcn_rcpf(den + 1e-8f);
    } else {
        onum[bh] = na;
        oden[bh] = da;
    }
}

extern "C" void kernel_launch(void* const* d_in, const int* in_sizes, int n_in,
                              void* d_out, int out_size, void* d_ws, size_t ws_size,
                              hipStream_t stream) {
    const float* inputs = (const float*)d_in[0];   // B x I
    const float* state  = (const float*)d_in[1];   // B x H
    const float* smu    = (const float*)d_in[2];   // I x H
    const float* ssig   = (const float*)d_in[3];
    const float* sW     = (const float*)d_in[4];
    const float* serev  = (const float*)d_in[5];
    const float* mu     = (const float*)d_in[6];   // H x H
    const float* sig    = (const float*)d_in[7];
    const float* W      = (const float*)d_in[8];
    const float* erev   = (const float*)d_in[9];
    const float* vleak  = (const float*)d_in[10];  // H
    const float* gleak  = (const float*)d_in[11];
    const float* cm     = (const float*)d_in[12];

    float* out  = (float*)d_out;                   // B x H
    char*  ws   = (char*)d_ws;
    const size_t MB = 1048576;
    float*  snum  = (float*)(ws);                  // 1MB
    float*  sden  = (float*)(ws + 1 * MB);         // 1MB
    float*  vA    = (float*)(ws + 2 * MB);         // 1MB ping buffer
    float4* rac   = (float4*)(ws + 3 * MB);        // 4MB  (H/2 x 512 x 16B)
    WPair*  rwp   = (WPair*) (ws + 7 * MB);        // 2MB
    float4* sac   = (float4*)(ws + 9 * MB);        // 2MB  (I/2 x 512 x 16B)
    WPair*  swp   = (WPair*) (ws + 11 * MB);       // 1MB

    // Prep: transform + pair-pack weights once per launch.
    ltc_prep<LTC_H><<<LTC_H * 256 / 256, 256, 0, stream>>>(mu, sig, W, erev, rac, rwp);
    ltc_prep<LTC_I><<<LTC_I * 256 / 256, 256, 0, stream>>>(smu, ssig, sW, serev, sac, swp);

    dim3 grid(LTC_H / 64, LTC_B / 4);              // (8, 128) = 1024 blocks
    dim3 blk(256);

    // Sensory pass: raw sums into ws.
    ltc_pass<LTC_I, false><<<grid, blk, 0, stream>>>(
        inputs, sac, swp, nullptr, nullptr, nullptr, nullptr, nullptr,
        snum, sden, nullptr);

    // 6 unfolds, ping-ponging so the last lands in d_out.
    const float* vin = state;
    float* targets[6] = {vA, out, vA, out, vA, out};
    for (int s = 0; s < 6; ++s) {
        ltc_pass<LTC_H, true><<<grid, blk, 0, stream>>>(
            vin, rac, rwp, snum, sden, vleak, gleak, cm,
            nullptr, nullptr, targets[s]);
        vin = targets[s];
    }
}